// Round 14
// baseline (520.681 us; speedup 1.0000x reference)
//
#include <hip/hip_runtime.h>

#define BB 4
#define CC 64
#define NNN 4096
#define OO 64
#define KK 20
#define EPSF 1e-5f

typedef __attribute__((ext_vector_type(4))) double d4;

// ---------------- K1: xx[n] = sum_c x[c][n]^2 in f64 ----------------
__global__ __launch_bounds__(256) void xx_kernel(const float* __restrict__ x, double* __restrict__ xx) {
    int g = blockIdx.x * 256 + threadIdx.x;          // 0..B*N-1
    int b = g >> 12, n = g & (NNN - 1);
    const float* xp = x + (size_t)b * CC * NNN + n;
    double s = 0.0;
    for (int c = 0; c < CC; ++c) {
        double v = (double)xp[(size_t)c * NNN];
        s += v * v;
    }
    xx[g] = s;
}

// ---------------- K2: per-point projections A = x*w1a^T, Bv = x*(w1b-w1a)^T ----------------
__global__ __launch_bounds__(256) void proj_kernel(const float* __restrict__ x, const float* __restrict__ w1,
                                                   float* __restrict__ A, float* __restrict__ Bv) {
    __shared__ float xs[CC][64];       // [c][p]
    __shared__ float ws1[OO][129];     // padded
    int tid = threadIdx.x;
    int b = blockIdx.x >> 6;
    int p0 = (blockIdx.x & 63) << 6;
    const float* xb = x + (size_t)b * CC * NNN;
    for (int i = tid; i < CC * 16; i += 256) {
        int c = i >> 4, q = i & 15;
        *(float4*)&xs[c][q * 4] = *(const float4*)(xb + (size_t)c * NNN + p0 + q * 4);
    }
    for (int i = tid; i < OO * 32; i += 256) {
        int o = i >> 5, q = i & 31;
        float4 v = *(const float4*)(w1 + o * 128 + q * 4);
        ws1[o][q * 4 + 0] = v.x; ws1[o][q * 4 + 1] = v.y;
        ws1[o][q * 4 + 2] = v.z; ws1[o][q * 4 + 3] = v.w;
    }
    __syncthreads();
    int ti = tid >> 4, tj = tid & 15;
    float aA[4][4] = {{0.f}}, aD[4][4] = {{0.f}};
    for (int c = 0; c < CC; ++c) {
        float4 xv4 = *(const float4*)&xs[c][ti * 4];
        float xv[4] = {xv4.x, xv4.y, xv4.z, xv4.w};
        #pragma unroll
        for (int oo = 0; oo < 4; ++oo) {
            float wa = ws1[tj * 4 + oo][c];
            float wd = ws1[tj * 4 + oo][64 + c] - wa;
            #pragma unroll
            for (int pp = 0; pp < 4; ++pp) {
                aA[pp][oo] = fmaf(xv[pp], wa, aA[pp][oo]);
                aD[pp][oo] = fmaf(xv[pp], wd, aD[pp][oo]);
            }
        }
    }
    size_t base = ((size_t)b * NNN + p0) * 64;
    #pragma unroll
    for (int pp = 0; pp < 4; ++pp) {
        int p = ti * 4 + pp;
        *(float4*)(A  + base + (size_t)p * 64 + tj * 4) = make_float4(aA[pp][0], aA[pp][1], aA[pp][2], aA[pp][3]);
        *(float4*)(Bv + base + (size_t)p * 64 + tj * 4) = make_float4(aD[pp][0], aD[pp][1], aD[pp][2], aD[pp][3]);
    }
}

// ---------------- K3: f64 MFMA distances, reg-A + rolling B-prefetch + setprio ----------------
// 1024 blocks (4/CU: LDS 33KB, VGPR<=128). Block = 16 rows x 4096 cands, 256-cand tiles.
// A-fragment (16 tile-invariant values/thread) in f32 registers -- no rowT LDS.
// B: rolling 4-deep named-register prefetch; steps 12..15 prefetch the NEXT tile's
// k=0..3 so loads stay in flight across epilogue+select. setprio(1) around MFMA chain.
// Selection/epilogue/probe: verbatim r13 (twice-validated).

__device__ __forceinline__ unsigned long long packkey(double d, int j) {
    unsigned long long u = __double_as_longlong(d);
    u ^= (unsigned long long)((long long)u >> 63) | 0x8000000000000000ULL;
    return (u & ~0xFFFULL) | (unsigned long long)(4095 - j);
}

__global__ __launch_bounds__(256, 4) void knn_kernel(const float* __restrict__ x, const double* __restrict__ xx,
                                                     int* __restrict__ idxOut) {
    __shared__ unsigned long long distK[16][258];// 33024 B -> 4 blocks/CU
    int tid = threadIdx.x;
    int lane = tid & 63, w = tid >> 6;           // 4 waves
    int b  = blockIdx.x >> 8;                    // 256 blocks per batch
    int r0 = (blockIdx.x & 255) * 16;
    const float* xb = x + (size_t)b * CC * NNN;
    const double* xxb = xx + (size_t)b * NNN;

    // ---- layout probe (2 MFMAs, once) ----
    double pv = (double)(lane & 15);
    d4 z4 = {0.0, 0.0, 0.0, 0.0};
    d4 pA = __builtin_amdgcn_mfma_f64_16x16x4f64(pv, 1.0, z4, 0, 0, 0);
    d4 pB = __builtin_amdgcn_mfma_f64_16x16x4f64(1.0, pv, z4, 0, 0, 0);
    int mA0 = (int)(pA[0] * 0.25), mA1 = (int)(pA[1] * 0.25),
        mA2 = (int)(pA[2] * 0.25), mA3 = (int)(pA[3] * 0.25);
    int mB0 = (int)(pB[0] * 0.25), mB1 = (int)(pB[1] * 0.25),
        mB2 = (int)(pB[2] * 0.25), mB3 = (int)(pB[3] * 0.25);

    int lr = lane & 15, lk = lane >> 4;
    double xr0 = xxb[r0 + mA0], xr1 = xxb[r0 + mA1],
           xr2 = xxb[r0 + mA2], xr3 = xxb[r0 + mA3];

    // ---- A-fragment in registers: c = 4k + lk, row = r0 + lr (tile-invariant) ----
    #define LDA(K) float rA##K = xb[(size_t)((K) * 4 + lk) * NNN + r0 + lr];
    LDA(0) LDA(1) LDA(2) LDA(3) LDA(4) LDA(5) LDA(6) LDA(7)
    LDA(8) LDA(9) LDA(10) LDA(11) LDA(12) LDA(13) LDA(14) LDA(15)
    #undef LDA

    // ---- rolling B prefetch registers (4 phases x 4 chains) ----
    float pB0_0, pB0_1, pB0_2, pB0_3, pB1_0, pB1_1, pB1_2, pB1_3,
          pB2_0, pB2_1, pB2_2, pB2_3, pB3_0, pB3_1, pB3_2, pB3_3;
    #define PF(P, J0, K) { \
        const float* gp_ = xb + (size_t)((K) * 4 + lk) * NNN + (J0) + w * 64 + lr; \
        pB##P##_0 = gp_[0];  pB##P##_1 = gp_[16]; \
        pB##P##_2 = gp_[32]; pB##P##_3 = gp_[48]; }
    #define CONS(P, K) { \
        double av_ = (double)rA##K; \
        acc0 = __builtin_amdgcn_mfma_f64_16x16x4f64(av_, (double)pB##P##_0, acc0, 0, 0, 0); \
        acc1 = __builtin_amdgcn_mfma_f64_16x16x4f64(av_, (double)pB##P##_1, acc1, 0, 0, 0); \
        acc2 = __builtin_amdgcn_mfma_f64_16x16x4f64(av_, (double)pB##P##_2, acc2, 0, 0, 0); \
        acc3 = __builtin_amdgcn_mfma_f64_16x16x4f64(av_, (double)pB##P##_3, acc3, 0, 0, 0); }

    // per-wave sorted lists for rows w*4..w*4+3 (ascending across lanes 0..19)
    unsigned long long S0, S1, S2, S3;
    S0 = S1 = S2 = S3 = (lane < KK) ? 0ULL : ~0ULL;
    unsigned long long T0 = 0, T1 = 0, T2 = 0, T3 = 0;

    #define SELROW(RL) { \
        for (int hf = 0; hf < 4; ++hf) { \
            unsigned long long key = distK[w * 4 + RL][hf * 64 + lane]; \
            unsigned long long m = __ballot(key > T##RL); \
            while (m) { \
                int src = (int)__builtin_ctzll(m); m &= m - 1; \
                unsigned long long kb = __shfl(key, src); \
                if (kb > T##RL) { \
                    unsigned long long u = __shfl_down(S##RL, 1); \
                    unsigned long long mx = (S##RL < kb) ? kb : S##RL; \
                    S##RL = (u < kb) ? u : mx; \
                    T##RL = __shfl(S##RL, 0); \
                } \
            } \
        } \
    }
    #define SELALL() SELROW(0) SELROW(1) SELROW(2) SELROW(3)

    PF(0, 0, 0) PF(1, 0, 1) PF(2, 0, 2) PF(3, 0, 3)
    for (int t = 0; t < 16; ++t) {
        int j0 = t * 256;
        int j0n = ((t + 1) & 15) * 256;            // wrap at t=15: harmless re-read
        d4 acc0 = {0.0, 0.0, 0.0, 0.0}, acc1 = {0.0, 0.0, 0.0, 0.0};
        d4 acc2 = {0.0, 0.0, 0.0, 0.0}, acc3 = {0.0, 0.0, 0.0, 0.0};
        __builtin_amdgcn_s_setprio(1);
        CONS(0, 0)   PF(0, j0, 4)
        CONS(1, 1)   PF(1, j0, 5)
        CONS(2, 2)   PF(2, j0, 6)
        CONS(3, 3)   PF(3, j0, 7)
        CONS(0, 4)   PF(0, j0, 8)
        CONS(1, 5)   PF(1, j0, 9)
        CONS(2, 6)   PF(2, j0, 10)
        CONS(3, 7)   PF(3, j0, 11)
        CONS(0, 8)   PF(0, j0, 12)
        CONS(1, 9)   PF(1, j0, 13)
        CONS(2, 10)  PF(2, j0, 14)
        CONS(3, 11)  PF(3, j0, 15)
        CONS(0, 12)  PF(0, j0n, 0)                 // next tile's k=0..3:
        CONS(1, 13)  PF(1, j0n, 1)                 // in flight across barriers/select
        CONS(2, 14)  PF(2, j0n, 2)
        CONS(3, 15)  PF(3, j0n, 3)
        __builtin_amdgcn_s_setprio(0);
        __syncthreads();                   // A: select(t-1) finished reading distK
        // ---- epilogue: measured labels; chain Q covers col w*64 + Q*16 + mB_i ----
        #define EPI(Q, R) { \
            int col = w * 64 + Q * 16 + mB##R; \
            double xq = xxb[j0 + col]; \
            distK[mA##R][col] = packkey(2.0 * acc##Q[R] - xr##R - xq, j0 + col); \
        }
        EPI(0,0) EPI(0,1) EPI(0,2) EPI(0,3)
        EPI(1,0) EPI(1,1) EPI(1,2) EPI(1,3)
        EPI(2,0) EPI(2,1) EPI(2,2) EPI(2,3)
        EPI(3,0) EPI(3,1) EPI(3,2) EPI(3,3)
        #undef EPI
        __syncthreads();                   // B: distK(t) ready
        SELALL();                          // select(t); next compute overlaps naturally
    }
    #undef SELALL
    #undef SELROW
    #undef PF
    #undef CONS

    if (lane < KK) {                       // lists ascending -> out descending
        size_t base = ((size_t)b * NNN + r0 + w * 4) * KK;
        idxOut[base + 0 * KK + (KK - 1 - lane)] = 4095 - (int)(S0 & 0xFFFULL);
        idxOut[base + 1 * KK + (KK - 1 - lane)] = 4095 - (int)(S1 & 0xFFFULL);
        idxOut[base + 2 * KK + (KK - 1 - lane)] = 4095 - (int)(S2 & 0xFFFULL);
        idxOut[base + 3 * KK + (KK - 1 - lane)] = 4095 - (int)(S3 & 0xFFFULL);
    }
}

// ---------------- K4: h1 = relu(bn1(A[nb]+Bv[n])); h2 = relu(bn2(h1·w2^T)); max over k ----------------
__global__ __launch_bounds__(256) void edge_kernel(const float* __restrict__ A, const float* __restrict__ Bv,
        const int* __restrict__ idx, const float* __restrict__ w2,
        const float* __restrict__ g1, const float* __restrict__ be1, const float* __restrict__ m1, const float* __restrict__ v1,
        const float* __restrict__ g2, const float* __restrict__ be2, const float* __restrict__ m2, const float* __restrict__ v2,
        float* __restrict__ out) {
    __shared__ float h1buf[4][KK][64];
    __shared__ float resT[64][33];
    int tid = threadIdx.x;
    int lane = tid & 63, w = tid >> 6;
    int b = blockIdx.x >> 7;
    int n0 = (blockIdx.x & 127) * 32;
    float s1 = g1[lane] * rsqrtf(v1[lane] + EPSF);
    float bb1 = be1[lane] - m1[lane] * s1;
    float s2 = g2[lane] * rsqrtf(v2[lane] + EPSF);
    float bb2 = be2[lane] - m2[lane] * s2;
    float w2r[64];
    #pragma unroll
    for (int o = 0; o < 64; ++o) w2r[o] = w2[lane * 64 + o];
    for (int p = 0; p < 8; ++p) {
        int n = n0 + w * 8 + p;
        size_t pb = (size_t)b * NNN + n;
        float bv = Bv[pb * 64 + lane];
        const int* ip = idx + pb * KK;
        #pragma unroll
        for (int k = 0; k < KK; ++k) {
            int nb = ip[k];
            float av = A[((size_t)b * NNN + nb) * 64 + lane];
            h1buf[w][k][lane] = fmaxf(0.f, fmaf(av + bv, s1, bb1));
        }
        __syncthreads();
        float mx = -1e30f;
        for (int k = 0; k < KK; ++k) {
            const float4* hb = (const float4*)&h1buf[w][k][0];
            float dot = 0.f;
            #pragma unroll
            for (int o4 = 0; o4 < 16; ++o4) {
                float4 h = hb[o4];
                dot = fmaf(w2r[o4 * 4 + 0], h.x, dot);
                dot = fmaf(w2r[o4 * 4 + 1], h.y, dot);
                dot = fmaf(w2r[o4 * 4 + 2], h.z, dot);
                dot = fmaf(w2r[o4 * 4 + 3], h.w, dot);
            }
            mx = fmaxf(mx, fmaxf(0.f, fmaf(dot, s2, bb2)));
        }
        resT[lane][w * 8 + p] = mx;
        __syncthreads();
    }
    for (int i = tid; i < 64 * 32; i += 256) {
        int o2 = i >> 5, pp = i & 31;
        out[((size_t)b * 64 + o2) * NNN + n0 + pp] = resT[o2][pp];
    }
}

extern "C" void kernel_launch(void* const* d_in, const int* in_sizes, int n_in,
                              void* d_out, int out_size, void* d_ws, size_t ws_size,
                              hipStream_t stream) {
    const float* x   = (const float*)d_in[0];
    const float* w1  = (const float*)d_in[1];
    const float* g1  = (const float*)d_in[2];
    const float* be1 = (const float*)d_in[3];
    const float* m1  = (const float*)d_in[4];
    const float* v1  = (const float*)d_in[5];
    const float* w2  = (const float*)d_in[6];
    const float* g2  = (const float*)d_in[7];
    const float* be2 = (const float*)d_in[8];
    const float* m2  = (const float*)d_in[9];
    const float* v2  = (const float*)d_in[10];
    // ws layout: xx f64 (128KB) | A f32 (4MB) | Bv f32 (4MB) | idx i32 (1.25MB)
    char* ws = (char*)d_ws;
    double* xx = (double*)ws;
    float*  A  = (float*)(ws + 131072);
    float*  Bv = (float*)(ws + 131072 + 4194304);
    int*    nidx = (int*)(ws + 131072 + 2 * 4194304);
    float*  out = (float*)d_out;

    hipLaunchKernelGGL(xx_kernel,   dim3(BB * NNN / 256), dim3(256), 0, stream, x, xx);
    hipLaunchKernelGGL(proj_kernel, dim3(BB * (NNN / 64)), dim3(256), 0, stream, x, w1, A, Bv);
    hipLaunchKernelGGL(knn_kernel,  dim3(BB * (NNN / 16)), dim3(256), 0, stream, x, xx, nidx);
    hipLaunchKernelGGL(edge_kernel, dim3(BB * (NNN / 32)), dim3(256), 0, stream,
                       A, Bv, nidx, w2, g1, be1, m1, v1, g2, be2, m2, v2, out);
}